// Round 1
// baseline (317.085 us; speedup 1.0000x reference)
//
#include <hip/hip_runtime.h>
#include <hip/hip_bf16.h>
#include <math.h>

typedef _Float16 f16;
typedef __attribute__((ext_vector_type(8))) _Float16 f16x8;
typedef __attribute__((ext_vector_type(4))) _Float16 f16x4;
typedef __attribute__((ext_vector_type(4))) float f32x4;

#define EMBED 1024
#define NHEADS 16
#define HDIM 64
#define BATCH 2
#define SEQ 2048
#define BS 4096  // BATCH*SEQ

// ---------------- ws layout (bytes) ----------------
// Xh:      0         (BS*EMBED f16       = 8388608)
// Wqkv_t:  8388608   (3072*1024 f16      = 6291456)
// Wout_t:  14680064  (1024*1024 f16      = 2097152)
// Qw:      16777216  (32*2048*64 f16     = 8388608)
// Kw:      25165824
// Vw:      33554432
// Ow:      41943040  ([B][S][H*64] f16   = 8388608)
// btab:    50331648  (16*4095 f32        = 262080)
// total ~50.6 MB

__device__ __forceinline__ f32x4 mfma16(f16x8 a, f16x8 b, f32x4 c) {
  return __builtin_amdgcn_mfma_f32_16x16x32_f16(a, b, c, 0, 0, 0);
}

// ---------------- cast fp32 -> fp16 ----------------
__global__ void cast_x_kernel(const float* __restrict__ src, f16* __restrict__ dst) {
  int i = (blockIdx.x * 256 + threadIdx.x) * 4;
  float4 v = *(const float4*)(src + i);
  f16x4 o = { (f16)v.x, (f16)v.y, (f16)v.z, (f16)v.w };
  *(f16x4*)(dst + i) = o;
}

// ------------- transpose + cast: in[K][N] fp32 -> out[N][K] fp16 -------------
__global__ void transpose_cast_kernel(const float* __restrict__ in, f16* __restrict__ out,
                                      int K, int N) {
  __shared__ float tile[32][33];
  int n0 = blockIdx.x * 32, k0 = blockIdx.y * 32;
  int tx = threadIdx.x & 31, ty = threadIdx.x >> 5;  // 256 thr: ty 0..7
#pragma unroll
  for (int r = ty; r < 32; r += 8) tile[r][tx] = in[(size_t)(k0 + r) * N + n0 + tx];
  __syncthreads();
#pragma unroll
  for (int r = ty; r < 32; r += 8) out[(size_t)(n0 + r) * K + k0 + tx] = (f16)tile[tx][r];
}

// ------------- relative-position bias table: btab[h][rp+2047] -------------
__global__ void bias_table_kernel(const float* __restrict__ rel_emb, float* __restrict__ btab) {
  int idx = blockIdx.x * 256 + threadIdx.x;  // 0..4094
  if (idx >= 4095) return;
  int rp = idx - 2047;                       // rp = k - q
  int rb = rp > 0 ? 16 : 0;
  int arp = rp < 0 ? -rp : rp;
  int loc;
  if (arp < 8) {
    loc = arp;
  } else {
    // log(arp/8)/log(16) * 8, truncated; matches reference within one bucket
    float lr = logf((float)arp * 0.125f) * (1.0f / 2.7725887222397811f);
    int t = 8 + (int)(lr * 8.0f);
    loc = t < 15 ? t : 15;
  }
  int bucket = rb + loc;
#pragma unroll
  for (int h = 0; h < 16; h++) btab[h * 4095 + idx] = rel_emb[bucket * 16 + h];
}

// ------------- shared GEMM core: C[128x128] = A[MxK] * Bt[NxK]^T -------------
// 256 threads = 4 waves (2x2), each wave a 64x64 quadrant as 4x4 MFMA blocks.
__device__ __forceinline__ void gemm_core(const f16* __restrict__ A, const f16* __restrict__ Bt,
                                          int m0, int n0, int Kdim, f32x4 (&acc)[4][4]) {
  __shared__ __align__(16) f16 As[128 * 40];  // [m][k] stride 40 (80 B rows, 16B-aligned)
  __shared__ __align__(16) f16 Bs[128 * 40];  // [n][k] stride 40

  int tid = threadIdx.x;
  int lane = tid & 63, wave = tid >> 6;
  int l15 = lane & 15, quad = lane >> 4;
  int wr = (wave >> 1) * 64, wc = (wave & 1) * 64;

#pragma unroll
  for (int i = 0; i < 4; i++)
#pragma unroll
    for (int j = 0; j < 4; j++) acc[i][j] = f32x4{0.f, 0.f, 0.f, 0.f};

  for (int kt = 0; kt < Kdim / 32; kt++) {
    int kk = kt * 32;
#pragma unroll
    for (int c = 0; c < 2; c++) {
      int i = c * 256 + tid;            // 0..511 chunks of 8 f16
      int row = i >> 2, cc = (i & 3) * 8;
      int4 av = *(const int4*)(A + (size_t)(m0 + row) * Kdim + kk + cc);
      int4 bv = *(const int4*)(Bt + (size_t)(n0 + row) * Kdim + kk + cc);
      *(int4*)(&As[row * 40 + cc]) = av;
      *(int4*)(&Bs[row * 40 + cc]) = bv;
    }
    __syncthreads();
    f16x8 af[4], bf[4];
#pragma unroll
    for (int i = 0; i < 4; i++) af[i] = *(const f16x8*)(&As[(wr + i * 16 + l15) * 40 + quad * 8]);
#pragma unroll
    for (int j = 0; j < 4; j++) bf[j] = *(const f16x8*)(&Bs[(wc + j * 16 + l15) * 40 + quad * 8]);
#pragma unroll
    for (int i = 0; i < 4; i++)
#pragma unroll
      for (int j = 0; j < 4; j++) acc[i][j] = mfma16(af[i], bf[j], acc[i][j]);
    __syncthreads();
  }
}

// ------------- GEMM1: qkv = Xh @ Wqkv_t^T, scatter to Q/K/V [B*H][S][D] f16 -------------
__global__ __launch_bounds__(256, 2) void gemm_qkv_kernel(
    const f16* __restrict__ Xh, const f16* __restrict__ Wt,
    f16* __restrict__ Q, f16* __restrict__ K_, f16* __restrict__ V_) {
  f32x4 acc[4][4];
  int m0 = blockIdx.y * 128, n0 = blockIdx.x * 128;
  gemm_core(Xh, Wt, m0, n0, 1024, acc);

  int lane = threadIdx.x & 63, wave = threadIdx.x >> 6;
  int l15 = lane & 15, quad = lane >> 4;
  int wr = (wave >> 1) * 64, wc = (wave & 1) * 64;
  // which/h are uniform per 64-col wave quadrant
  int nq = n0 + wc;
  int which = nq >> 10;
  int h = (nq >> 6) & 15;
  f16* base = which == 0 ? Q : (which == 1 ? K_ : V_);
#pragma unroll
  for (int i = 0; i < 4; i++) {
#pragma unroll
    for (int j = 0; j < 4; j++) {
      int d = j * 16 + l15;  // nq is 64-aligned so d = (n & 63)
#pragma unroll
      for (int r = 0; r < 4; r++) {
        int m = m0 + wr + i * 16 + quad * 4 + r;
        int b = m >> 11, s = m & 2047;
        base[(((size_t)(b * 16 + h) * 2048 + s) << 6) + d] = (f16)acc[i][j][r];
      }
    }
  }
}

// ------------- flash attention: one block = 64 q-rows of one (b,h) -------------
__global__ __launch_bounds__(256, 2) void attn_kernel(
    const f16* __restrict__ Q, const f16* __restrict__ K_, const f16* __restrict__ V_,
    const float* __restrict__ btab, f16* __restrict__ O) {
  __shared__ float bias_lds[2112];              // bias for rp = k - (qbase+row64), idx = k - row64 + 63
  __shared__ __align__(16) f16 Vt[64 * 72];     // transposed V tile [d][kk], stride 72
  __shared__ __align__(16) f16 Pl[4][16 * 72];  // per-wave P tile [row][kk], stride 72

  int qt = blockIdx.x, bh = blockIdx.y;
  int qbase = qt * 64;
  int h = bh & 15, b = bh >> 4;
  int tid = threadIdx.x, lane = tid & 63, wave = tid >> 6;
  int l15 = lane & 15, quad = lane >> 4;

  // stage per-head bias row (2111 entries used: idx 0..2110)
  const float* brow = btab + h * 4095 + (1984 - qbase);
  for (int i = tid; i < 2111; i += 256) bias_lds[i] = brow[i];

  // Q fragments for this wave's 16 rows (A-operand layout), loaded once
  const f16* qptr = Q + ((size_t)bh * 2048 + qbase + wave * 16 + l15) * 64 + quad * 8;
  f16x8 qf[2];
  qf[0] = *(const f16x8*)(qptr);
  qf[1] = *(const f16x8*)(qptr + 32);

  f32x4 accO[4] = {};
  float m_i[4], l_i[4];
#pragma unroll
  for (int r = 0; r < 4; r++) { m_i[r] = -INFINITY; l_i[r] = 0.f; }

  const f16* kbp = K_ + (size_t)bh * 2048 * 64;
  const f16* vbp = V_ + (size_t)bh * 2048 * 64;

  __syncthreads();  // bias ready; Vt region safe to write

  for (int kt = 0; kt < 32; kt++) {
    int kb = kt * 64;
    // stage V tile transposed: Vt[d][kk]
#pragma unroll
    for (int c = 0; c < 2; c++) {
      int i = c * 256 + tid;  // 0..511
      int krow = i >> 3, dc = (i & 7) * 8;
      f16x8 vv = *(const f16x8*)(vbp + (size_t)(kb + krow) * 64 + dc);
#pragma unroll
      for (int j = 0; j < 8; j++) Vt[(dc + j) * 72 + krow] = vv[j];
    }
    __syncthreads();

    // S tile = Q K^T (16 rows x 64 keys per wave)
    f32x4 sc[4] = {};
#pragma unroll
    for (int t = 0; t < 2; t++) {
#pragma unroll
      for (int c = 0; c < 4; c++) {
        f16x8 kf = *(const f16x8*)(kbp + (size_t)(kb + c * 16 + l15) * 64 + t * 32 + quad * 8);
        sc[c] = mfma16(qf[t], kf, sc[c]);
      }
    }
    // + bias
#pragma unroll
    for (int c = 0; c < 4; c++) {
#pragma unroll
      for (int r = 0; r < 4; r++) {
        int row64 = wave * 16 + quad * 4 + r;
        sc[c][r] += bias_lds[kb + c * 16 + l15 + 63 - row64];
      }
    }
    // online softmax (row stats live across 16 lanes of same quad)
#pragma unroll
    for (int r = 0; r < 4; r++) {
      float mx = fmaxf(fmaxf(sc[0][r], sc[1][r]), fmaxf(sc[2][r], sc[3][r]));
#pragma unroll
      for (int off = 8; off; off >>= 1) mx = fmaxf(mx, __shfl_xor(mx, off));
      float mn = fmaxf(m_i[r], mx);
      float al = __expf(m_i[r] - mn);
      float rs = 0.f;
#pragma unroll
      for (int c = 0; c < 4; c++) {
        float p = __expf(sc[c][r] - mn);
        sc[c][r] = p;
        rs += p;
      }
#pragma unroll
      for (int off = 8; off; off >>= 1) rs += __shfl_xor(rs, off);
      l_i[r] = l_i[r] * al + rs;
      m_i[r] = mn;
#pragma unroll
      for (int c = 0; c < 4; c++) accO[c][r] *= al;
    }
    // P -> LDS (C-layout to A-layout round trip), wave-local region
    f16* pw = &Pl[wave][0];
#pragma unroll
    for (int c = 0; c < 4; c++)
#pragma unroll
      for (int r = 0; r < 4; r++)
        pw[(quad * 4 + r) * 72 + c * 16 + l15] = (f16)sc[c][r];

    // O += P @ V
#pragma unroll
    for (int t = 0; t < 2; t++) {
      f16x8 pf = *(const f16x8*)(pw + l15 * 72 + t * 32 + quad * 8);
#pragma unroll
      for (int c = 0; c < 4; c++) {
        f16x8 vf = *(const f16x8*)(&Vt[(c * 16 + l15) * 72 + t * 32 + quad * 8]);
        accO[c] = mfma16(pf, vf, accO[c]);
      }
    }
    __syncthreads();  // protect Vt before next stage
  }

  // epilogue: O/l -> Ow [b][s][h*64+d] f16
#pragma unroll
  for (int r = 0; r < 4; r++) {
    float invl = 1.0f / l_i[r];
    int srow = qbase + wave * 16 + quad * 4 + r;
    f16* op = O + ((size_t)(b * 2048 + srow) << 10) + h * 64;
#pragma unroll
    for (int c = 0; c < 4; c++) op[c * 16 + l15] = (f16)(accO[c][r] * invl);
  }
}

// ------------- GEMM2: out = Ow @ Wout_t^T (fp32 out) -------------
__global__ __launch_bounds__(256, 2) void gemm_out_kernel(
    const f16* __restrict__ Oh, const f16* __restrict__ Wt, float* __restrict__ out) {
  f32x4 acc[4][4];
  int m0 = blockIdx.y * 128, n0 = blockIdx.x * 128;
  gemm_core(Oh, Wt, m0, n0, 1024, acc);

  int lane = threadIdx.x & 63, wave = threadIdx.x >> 6;
  int l15 = lane & 15, quad = lane >> 4;
  int wr = (wave >> 1) * 64, wc = (wave & 1) * 64;
#pragma unroll
  for (int i = 0; i < 4; i++) {
#pragma unroll
    for (int j = 0; j < 4; j++) {
      int n = n0 + wc + j * 16 + l15;
#pragma unroll
      for (int r = 0; r < 4; r++) {
        int m = m0 + wr + i * 16 + quad * 4 + r;
        out[((size_t)m << 10) + n] = acc[i][j][r];
      }
    }
  }
}

extern "C" void kernel_launch(void* const* d_in, const int* in_sizes, int n_in,
                              void* d_out, int out_size, void* d_ws, size_t ws_size,
                              hipStream_t stream) {
  const float* X = (const float*)d_in[0];     // (2,2048,1024)
  const float* Wqkv = (const float*)d_in[1];  // (1024,3072)
  const float* Wout = (const float*)d_in[2];  // (1024,1024)
  const float* rel = (const float*)d_in[3];   // (32,16)

  char* ws = (char*)d_ws;
  f16* Xh     = (f16*)(ws + 0);
  f16* Wqkv_t = (f16*)(ws + 8388608);
  f16* Wout_t = (f16*)(ws + 14680064);
  f16* Qw     = (f16*)(ws + 16777216);
  f16* Kw     = (f16*)(ws + 25165824);
  f16* Vw     = (f16*)(ws + 33554432);
  f16* Ow     = (f16*)(ws + 41943040);
  float* btab = (float*)(ws + 50331648);

  cast_x_kernel<<<4096, 256, 0, stream>>>(X, Xh);
  transpose_cast_kernel<<<dim3(96, 32), 256, 0, stream>>>(Wqkv, Wqkv_t, 1024, 3072);
  transpose_cast_kernel<<<dim3(32, 32), 256, 0, stream>>>(Wout, Wout_t, 1024, 1024);
  bias_table_kernel<<<16, 256, 0, stream>>>(rel, btab);
  gemm_qkv_kernel<<<dim3(24, 32), 256, 0, stream>>>(Xh, Wqkv_t, Qw, Kw, Vw);
  attn_kernel<<<dim3(32, 32), 256, 0, stream>>>(Qw, Kw, Vw, btab, Ow);
  gemm_out_kernel<<<dim3(8, 32), 256, 0, stream>>>(Ow, Wout_t, (float*)d_out);
}